// Round 2
// baseline (334.450 us; speedup 1.0000x reference)
//
#include <hip/hip_runtime.h>

// LabelWiseMLC: out[b,l] = sigmoid(dot(doc_rep[b,l,:], W[l,:]) + bias[l])
// B=128, L=512, I=1024, fp32. doc (268 MB) streamed once; roofline ~43 us.
//
// v3: contiguous-stream restructure.
// Forensics: graded dur (~330us) = ~161us harness poison fill (1 GiB, fixed)
// + kernel (~160us = 1.7 TB/s). v1/v2 both walked 8 rows at 2-MB stride per
// wave (128 interleaved 4-KB streams per CU) -- suspected DRAM stream-scatter
// cap. v3 makes every block read one CONTIGUOUS 32-KB chunk, with
// consecutive blocks continuing the linear sweep of doc.
//
// Block (256 thr) = (b, lg): processes labels [8lg, 8lg+8) of batch row b.
//   doc chunk: doc[b][8lg..8lg+8)[:]  = 32 KB contiguous
//   W chunk:   W[8lg..8lg+8)[:]       = 32 KB, read from global each block.
//     W total is 2 MB -> resident in every XCD's 4-MB L2; 268 MB of W reads
//     are L2-served (34.5 TB/s aggregate ~ 8us equivalent, hidden).
// Row k (k=0..7) is exactly 256 float4 -> thread t owns float4 #t of row k.
// Per thread: 8 doc loads (nontemporal: zero reuse, keep W unevicted in L2)
// + 8 W loads + 32 FMA, all loads issued up front (16 KB/wave in flight).
// Reduction deferred to the end: folded 64-lane butterfly (10 shfl for all
// 8 rows; row-sum m lands on lane 8m) + 128-B LDS combine across 4 waves.

#define B_DIM 128
#define L_DIM 512
#define I_DIM 1024
#define LG 8  // labels per block

typedef float vfloat4 __attribute__((ext_vector_type(4)));

__global__ __launch_bounds__(256) void labelwise_mlc_kernel(
    const float* __restrict__ doc,   // (B, L, I)
    const float* __restrict__ W,     // (L, I)
    const float* __restrict__ bias,  // (L,)
    float* __restrict__ out)         // (B, L)
{
    const int t    = threadIdx.x;
    const int lane = t & 63;
    const int wid  = t >> 6;
    const int lg   = blockIdx.x & (L_DIM / LG - 1);  // label group 0..63
    const int b    = blockIdx.x >> 6;                // batch row 0..127

    const vfloat4* __restrict__ dp = (const vfloat4*)doc +
        (size_t)b * (L_DIM * I_DIM / 4) + (size_t)lg * (LG * I_DIM / 4);
    const vfloat4* __restrict__ wp = (const vfloat4*)W +
        (size_t)lg * (LG * I_DIM / 4);

    // ---- load phase: 16 independent 16-B loads issued up front ----
    vfloat4 d[LG], w[LG];
#pragma unroll
    for (int k = 0; k < LG; ++k) {
        const int o = k * 256 + t;  // row k, float4 #t
        d[k] = __builtin_nontemporal_load(dp + o);
        w[k] = wp[o];
    }

    // ---- per-thread partials ----
    float acc[LG];
#pragma unroll
    for (int k = 0; k < LG; ++k) {
        float a = d[k].x * w[k].x;
        a = fmaf(d[k].y, w[k].y, a);
        a = fmaf(d[k].z, w[k].z, a);
        a = fmaf(d[k].w, w[k].w, a);
        acc[k] = a;
    }

    // ---- folded butterfly: 8 row-partials -> lane 8m holds wave-sum of m ----
    const bool hi5 = (lane & 32) != 0;
    float r[4];
#pragma unroll
    for (int i = 0; i < 4; ++i) {
        const float mine = hi5 ? acc[i + 4] : acc[i];
        const float send = hi5 ? acc[i] : acc[i + 4];
        r[i] = mine + __shfl_xor(send, 32, 64);
    }
    const bool hi4 = (lane & 16) != 0;
    float s2[2];
#pragma unroll
    for (int i = 0; i < 2; ++i) {
        const float mine = hi4 ? r[i + 2] : r[i];
        const float send = hi4 ? r[i] : r[i + 2];
        s2[i] = mine + __shfl_xor(send, 16, 64);
    }
    const bool hi3 = (lane & 8) != 0;
    float s0;
    {
        const float mine = hi3 ? s2[1] : s2[0];
        const float send = hi3 ? s2[0] : s2[1];
        s0 = mine + __shfl_xor(send, 8, 64);
    }
    s0 += __shfl_xor(s0, 4, 64);
    s0 += __shfl_xor(s0, 2, 64);
    s0 += __shfl_xor(s0, 1, 64);

    // ---- cross-wave combine: 8 rows x 4 waves = 32 partials in LDS ----
    __shared__ float part[LG][4];
    if ((lane & 7) == 0) part[lane >> 3][wid] = s0;
    __syncthreads();

    if (t < 32) {
        const int m = t >> 2;   // row within group
        const int wv = t & 3;   // wave partial
        float v = part[m][wv];
        v += __shfl_xor(v, 1, 64);
        v += __shfl_xor(v, 2, 64);
        if (wv == 0) {
            const int l = lg * LG + m;
            const float z = v + bias[l];
            out[(size_t)b * L_DIM + l] = 1.0f / (1.0f + __expf(-z));
        }
    }
}

extern "C" void kernel_launch(void* const* d_in, const int* in_sizes, int n_in,
                              void* d_out, int out_size, void* d_ws, size_t ws_size,
                              hipStream_t stream) {
    const float* doc  = (const float*)d_in[0];  // (128, 512, 1024)
    const float* W    = (const float*)d_in[1];  // (512, 1024)
    const float* bias = (const float*)d_in[2];  // (512,)
    float* out = (float*)d_out;                 // (128, 512)

    // 8192 blocks = 128 b x 64 label-groups; consecutive blocks read
    // consecutive 32-KB doc chunks (linear sweep within each b).
    const int blocks = B_DIM * (L_DIM / LG);  // 8192
    labelwise_mlc_kernel<<<blocks, 256, 0, stream>>>(doc, W, bias, out);
}